// Round 3
// baseline (395.753 us; speedup 1.0000x reference)
//
#include <hip/hip_runtime.h>
#include <hip/hip_bf16.h>
#include <cstdint>

typedef unsigned short u16;
typedef __bf16 bf16x8 __attribute__((ext_vector_type(8)));
typedef float f32x4 __attribute__((ext_vector_type(4)));
typedef unsigned short u16x8 __attribute__((ext_vector_type(8)));
typedef unsigned short u16x4 __attribute__((ext_vector_type(4)));

#define B_ 2
#define T_ 2048
#define C_ 2048
#define NH_ 16
#define NKV_ 4
#define HD_ 128
// (1/sqrt(128)) * log2(e) — folded into Q at rope_rms time
#define K2_ 0.12752004650581538f

__device__ __forceinline__ u16 f2bf(float f) {
    unsigned u = __builtin_bit_cast(unsigned, f);
    unsigned r = u + 0x7FFFu + ((u >> 16) & 1u);
    return (u16)(r >> 16);
}

__device__ __forceinline__ void gl16(const void* g, void* l) {
    auto gp = reinterpret_cast<const __attribute__((address_space(1))) unsigned*>(
        reinterpret_cast<uintptr_t>(g));
    auto lp = reinterpret_cast<__attribute__((address_space(3))) unsigned*>(
        reinterpret_cast<uintptr_t>(l));
    __builtin_amdgcn_global_load_lds(gp, lp, 16, 0, 0);
}

// ---------- transpose + fp32->bf16 convert: in [2048][N] -> out [N][2048] ----------
__global__ void transpose_conv(const float* __restrict__ in, u16* __restrict__ out, int N) {
    __shared__ float tile[32][33];
    int n0 = blockIdx.x * 32, k0 = blockIdx.y * 32;
    int tx = threadIdx.x, ty = threadIdx.y;  // 32 x 8
#pragma unroll
    for (int i = 0; i < 4; ++i)
        tile[ty * 4 + i][tx] = in[(size_t)(k0 + ty * 4 + i) * N + n0 + tx];
    __syncthreads();
#pragma unroll
    for (int i = 0; i < 4; ++i)
        out[(size_t)(n0 + ty * 4 + i) * 2048 + k0 + tx] = f2bf(tile[tx][ty * 4 + i]);
}

// ---------- fp32 -> bf16 convert (x), 4 elems/thread ----------
__global__ void convert4(const float4* __restrict__ in, u16* __restrict__ out) {
    int i = blockIdx.x * 256 + threadIdx.x;
    float4 v = in[i];
    u16x4 o;
    o[0] = f2bf(v.x); o[1] = f2bf(v.y); o[2] = f2bf(v.z); o[3] = f2bf(v.w);
    ((u16x4*)out)[i] = o;
}

// ---------- GEMM: C[M][N] f32 = A[M][K] bf16 * BT[N][K] bf16 (B transposed) ----------
__global__ __launch_bounds__(256, 2) void gemm_bf16(const u16* __restrict__ A,
                                                    const u16* __restrict__ BT,
                                                    float* __restrict__ C, int N, int K) {
    __shared__ __align__(16) u16 As[128 * 64];
    __shared__ __align__(16) u16 Bs[128 * 64];
    int t = threadIdx.x;
    int w = t >> 6, l = t & 63;
    int wr = w >> 1, wc = w & 1;
    int lg = l >> 4, lr = l & 15;
    int m0 = blockIdx.y * 128, n0 = blockIdx.x * 128;
    f32x4 acc[4][4] = {};

    int ar = t >> 3;
    int acb = (t & 7) * 16;
    const char* Abase = (const char*)(A + (size_t)(m0 + ar) * K) + acb;
    const char* Bbase = (const char*)(BT + (size_t)(n0 + ar) * K) + acb;
    char* AsB = (char*)As + t * 16;
    char* BsB = (char*)Bs + t * 16;

    for (int kt = 0; kt < K; kt += 64) {
        if (kt) __syncthreads();
#pragma unroll
        for (int i = 0; i < 4; ++i) {
            gl16(Abase + (size_t)(i * 32) * K * 2 + (size_t)kt * 2, AsB + i * 4096);
            gl16(Bbase + (size_t)(i * 32) * K * 2 + (size_t)kt * 2, BsB + i * 4096);
        }
        __syncthreads();
#pragma unroll
        for (int kk = 0; kk < 2; ++kk) {
            bf16x8 af[4], bfr[4];
#pragma unroll
            for (int m = 0; m < 4; ++m)
                af[m] = *(const bf16x8*)(As + (wr * 64 + m * 16 + lr) * 64 + kk * 32 + lg * 8);
#pragma unroll
            for (int n = 0; n < 4; ++n)
                bfr[n] = *(const bf16x8*)(Bs + (wc * 64 + n * 16 + lr) * 64 + kk * 32 + lg * 8);
#pragma unroll
            for (int m = 0; m < 4; ++m)
#pragma unroll
                for (int n = 0; n < 4; ++n)
                    acc[m][n] = __builtin_amdgcn_mfma_f32_16x16x32_bf16(af[m], bfr[n], acc[m][n], 0, 0, 0);
        }
    }
#pragma unroll
    for (int m = 0; m < 4; ++m) {
        int row = m0 + wr * 64 + m * 16 + lg * 4;
#pragma unroll
        for (int n = 0; n < 4; ++n) {
            int col = n0 + wc * 64 + n * 16 + lr;
            float* Cp = C + (size_t)row * N + col;
#pragma unroll
            for (int r = 0; r < 4; ++r)
                Cp[(size_t)r * N] = acc[m][n][r];
        }
    }
}

// ---------- RoPE + RMSNorm on q and k. One wave per 128-elem head-vector ----------
// q additionally pre-scaled by K2_ (softmax scale folded into Q, log2 domain)
__global__ void rope_rms(const float* __restrict__ qkv, const float* __restrict__ cs,
                         const float* __restrict__ sn, u16* __restrict__ qh,
                         u16* __restrict__ kh) {
    int task = blockIdx.x * 4 + (threadIdx.x >> 6);
    int l = threadIdx.x & 63;
    const float* in;
    u16* out;
    int tpos;
    float post = 1.0f;
    if (task < 65536) {               // q: 4096 rows * 16 heads
        int row = task >> 4, h = task & 15;
        in = qkv + (size_t)row * 3072 + h * 128;
        int b = row >> 11; tpos = row & 2047;
        out = qh + ((size_t)(b * NH_ + h) * T_ + tpos) * HD_;
        post = K2_;
    } else {                          // k: 4096 rows * 4 heads
        int t2 = task - 65536;
        int row = t2 >> 2, h = t2 & 3;
        in = qkv + (size_t)row * 3072 + 2048 + h * 128;
        int b = row >> 11; tpos = row & 2047;
        out = kh + ((size_t)(b * NKV_ + h) * T_ + tpos) * HD_;
    }
    float x1 = in[l], x2 = in[l + 64];
    float c = cs[tpos * 64 + l], s = sn[tpos * 64 + l];
    float o1 = x1 * c + x2 * s;
    float o2 = -x1 * s + x2 * c;
    float ss = o1 * o1 + o2 * o2;
#pragma unroll
    for (int m = 1; m < 64; m <<= 1) ss += __shfl_xor(ss, m);
    float r = rsqrtf(ss * (1.0f / 128.0f) + 1.1920929e-07f) * post;
    out[l] = f2bf(o1 * r);
    out[l + 64] = f2bf(o2 * r);
}

// ---------- V extract + transpose: qkv [4096][3072] f32 -> vt [B*NKV][128][2048] bf16 ----------
__global__ void transpose_v(const float* __restrict__ qkv, u16* __restrict__ vt) {
    __shared__ float tile[32][33];
    int t0 = blockIdx.x * 32;   // 64
    int d0 = blockIdx.y * 32;   // 4
    int bk = blockIdx.z;        // 8 = b*4+kvh
    int b = bk >> 2, kvh = bk & 3;
    int tx = threadIdx.x, ty = threadIdx.y;  // 32 x 8
#pragma unroll
    for (int i = 0; i < 4; ++i)
        tile[ty * 4 + i][tx] =
            qkv[(size_t)(b * 2048 + t0 + ty * 4 + i) * 3072 + 2560 + kvh * 128 + d0 + tx];
    __syncthreads();
#pragma unroll
    for (int i = 0; i < 4; ++i)
        vt[((size_t)bk * 128 + d0 + ty * 4 + i) * 2048 + t0 + tx] = f2bf(tile[tx][ty * 4 + i]);
}

// ---------- causal GQA flash attention ----------
// One wave per block, two 16-row strips per wave (p, 127-p) -> 33 kv-iters of 64 keys.
// Q pre-scaled; softmax in log2 domain; V prefetched to regs ahead of softmax.
__device__ __forceinline__ void attn_strip16(const u16* __restrict__ Qp,
                                             const u16* __restrict__ Kp,
                                             const u16* __restrict__ Vp,
                                             u16* __restrict__ Yp, int s, u16* P) {
    int l = threadIdx.x;
    int lg = l >> 4, lr = l & 15;
    int qw = s * 16;

    bf16x8 aq[4];
#pragma unroll
    for (int ch = 0; ch < 4; ++ch)
        aq[ch] = *(const bf16x8*)(Qp + (size_t)(qw + lr) * HD_ + ch * 32 + lg * 8);

    f32x4 acc[8] = {};
    float m2[4], lp[4];
#pragma unroll
    for (int r = 0; r < 4; ++r) { m2[r] = -1e30f; lp[r] = 0.0f; }

    int kend = qw + 16;
    for (int kv0 = 0; kv0 < kend; kv0 += 64) {
        bool nm = (kv0 + 63 >= qw);  // diagonal block needs causal mask
        // ---- S = Q K^T over 64 keys (K loads feed MFMA directly) ----
        f32x4 sc[4] = {};
#pragma unroll
        for (int ch = 0; ch < 4; ++ch)
#pragma unroll
            for (int kf = 0; kf < 4; ++kf) {
                bf16x8 bk = *(const bf16x8*)(Kp + (size_t)(kv0 + kf * 16 + lr) * HD_ + ch * 32 + lg * 8);
                sc[kf] = __builtin_amdgcn_mfma_f32_16x16x32_bf16(aq[ch], bk, sc[kf], 0, 0, 0);
            }
        // ---- prefetch V for this block into regs (latency hides under softmax) ----
        bf16x8 vreg[16];
#pragma unroll
        for (int oc = 0; oc < 8; ++oc)
#pragma unroll
            for (int kk = 0; kk < 2; ++kk)
                vreg[oc * 2 + kk] =
                    *(const bf16x8*)(Vp + (size_t)(oc * 16 + lr) * T_ + kv0 + kk * 32 + lg * 8);
        // ---- mask + row max (log2 domain, S already scaled) ----
        float sv[4][4], mx[4];
#pragma unroll
        for (int r = 0; r < 4; ++r) {
            int row = qw + lg * 4 + r;
#pragma unroll
            for (int kf = 0; kf < 4; ++kf) {
                float x = sc[kf][r];
                if (nm) {
                    int key = kv0 + kf * 16 + lr;
                    x = (key > row) ? -1e38f : x;
                }
                sv[r][kf] = x;
            }
            mx[r] = fmaxf(fmaxf(sv[r][0], sv[r][1]), fmaxf(sv[r][2], sv[r][3]));
        }
#pragma unroll
        for (int r = 0; r < 4; ++r) {
            float m = mx[r];
            m = fmaxf(m, __shfl_xor(m, 1));
            m = fmaxf(m, __shfl_xor(m, 2));
            m = fmaxf(m, __shfl_xor(m, 4));
            m = fmaxf(m, __shfl_xor(m, 8));
            mx[r] = m;
        }
        // ---- defer-max rescale (THR = 8 in log2 domain) ----
        bool upd = false;
#pragma unroll
        for (int r = 0; r < 4; ++r) upd |= (mx[r] > m2[r] + 8.0f);
        if (__any(upd)) {
#pragma unroll
            for (int r = 0; r < 4; ++r) {
                float mn = fmaxf(m2[r], mx[r]);
                float rs = exp2f(m2[r] - mn);
                m2[r] = mn;
                lp[r] *= rs;
#pragma unroll
                for (int oc = 0; oc < 8; ++oc) acc[oc][r] *= rs;
            }
        }
        // ---- p = 2^(s-m), partial l, stage P in LDS ----
#pragma unroll
        for (int r = 0; r < 4; ++r) {
            float m = m2[r];
            float ps = 0.0f;
#pragma unroll
            for (int kf = 0; kf < 4; ++kf) {
                float p = exp2f(sv[r][kf] - m);
                ps += p;
                P[(lg * 4 + r) * 72 + kf * 16 + lr] = f2bf(p);
            }
            lp[r] += ps;
        }
        // ---- O += P V ----
        bf16x8 ap[2];
#pragma unroll
        for (int kk = 0; kk < 2; ++kk)
            ap[kk] = *(const bf16x8*)&P[lr * 72 + kk * 32 + lg * 8];
#pragma unroll
        for (int oc = 0; oc < 8; ++oc)
#pragma unroll
            for (int kk = 0; kk < 2; ++kk)
                acc[oc] = __builtin_amdgcn_mfma_f32_16x16x32_bf16(ap[kk], vreg[oc * 2 + kk], acc[oc], 0, 0, 0);
    }
    // ---- epilogue ----
    float inv_[4];
#pragma unroll
    for (int r = 0; r < 4; ++r) {
        float lt = lp[r];
        lt += __shfl_xor(lt, 1);
        lt += __shfl_xor(lt, 2);
        lt += __shfl_xor(lt, 4);
        lt += __shfl_xor(lt, 8);
        inv_[r] = 1.0f / lt;
    }
#pragma unroll
    for (int oc = 0; oc < 8; ++oc)
#pragma unroll
        for (int r = 0; r < 4; ++r)
            Yp[(size_t)(qw + lg * 4 + r) * 2048 + oc * 16 + lr] = f2bf(acc[oc][r] * inv_[r]);
}

// grid: 2048 blocks of 64 thr. XCD-aware decode: x&7 -> (b,kvh) so each XCD's L2
// holds exactly one K/V pair (1 MB, resident).
__global__ __launch_bounds__(64, 2) void attn(const u16* __restrict__ Q,
                                              const u16* __restrict__ Kk,
                                              const u16* __restrict__ V,
                                              u16* __restrict__ Y) {
    __shared__ __align__(16) u16 P[16 * 72];
    int x = blockIdx.x;
    int xcd = x & 7;
    int b = xcd >> 2, kvh = xcd & 3;
    int r = x >> 3;             // 0..255
    int h = kvh * 4 + (r & 3);
    int pair = r >> 2;          // 0..63
    const u16* Qp = Q + (size_t)(b * NH_ + h) * T_ * HD_;
    const u16* Kp = Kk + (size_t)(b * NKV_ + kvh) * T_ * HD_;
    const u16* Vp = V + (size_t)(b * NKV_ + kvh) * HD_ * T_;
    u16* Yp = Y + (size_t)(b * T_) * 2048 + h * HD_;
    attn_strip16(Qp, Kp, Vp, Yp, pair, P);
    attn_strip16(Qp, Kp, Vp, Yp, 127 - pair, P);
}

extern "C" void kernel_launch(void* const* d_in, const int* in_sizes, int n_in,
                              void* d_out, int out_size, void* d_ws, size_t ws_size,
                              hipStream_t stream) {
    const float* x    = (const float*)d_in[0];
    const float* cosT = (const float*)d_in[1];
    const float* sinT = (const float*)d_in[2];
    const float* wq   = (const float*)d_in[3];
    const float* wk   = (const float*)d_in[4];
    const float* wv   = (const float*)d_in[5];
    const float* wo   = (const float*)d_in[6];
    float* out = (float*)d_out;

    char* ws = (char*)d_ws;
    u16*   wqkvT = (u16*)(ws);                       // [3072][2048] bf16
    u16*   woT   = (u16*)(ws + 12582912);            // [2048][2048] bf16
    u16*   xb    = (u16*)(ws + 20971520);            // [4096][2048] bf16
    float* qkv   = (float*)(ws + 37748736);          // [4096][3072] f32
    u16*   qh    = (u16*)(ws + 88080384);            // [2][16][2048][128] bf16
    u16*   kh    = (u16*)(ws + 104857600);           // [2][4][2048][128] bf16
    u16*   vt    = (u16*)(ws + 109051904);           // [2][4][128][2048] bf16 (V^T)
    u16*   y     = xb;                               // reuse (xb dead after GEMM1)

    transpose_conv<<<dim3(64, 64), dim3(32, 8), 0, stream>>>(wq, wqkvT, 2048);
    transpose_conv<<<dim3(16, 64), dim3(32, 8), 0, stream>>>(wk, wqkvT + (size_t)2048 * 2048, 512);
    transpose_conv<<<dim3(16, 64), dim3(32, 8), 0, stream>>>(wv, wqkvT + (size_t)2560 * 2048, 512);
    transpose_conv<<<dim3(64, 64), dim3(32, 8), 0, stream>>>(wo, woT, 2048);
    convert4<<<8192, 256, 0, stream>>>((const float4*)x, xb);

    gemm_bf16<<<dim3(24, 32), 256, 0, stream>>>(xb, wqkvT, qkv, 3072, 2048);

    rope_rms<<<20480, 256, 0, stream>>>(qkv, cosT, sinT, qh, kh);
    transpose_v<<<dim3(64, 4, 8), dim3(32, 8), 0, stream>>>(qkv, vt);

    attn<<<2048, 64, 0, stream>>>(qh, kh, vt, y);

    gemm_bf16<<<dim3(16, 32), 256, 0, stream>>>(y, woT, out, 2048, 2048);
}

// Round 4
// 236.741 us; speedup vs baseline: 1.6717x; 1.6717x over previous
//
#include <hip/hip_runtime.h>
#include <hip/hip_bf16.h>
#include <cstdint>

typedef unsigned short u16;
typedef __bf16 bf16x8 __attribute__((ext_vector_type(8)));
typedef float f32x4 __attribute__((ext_vector_type(4)));
typedef unsigned short u16x8 __attribute__((ext_vector_type(8)));
typedef unsigned short u16x4 __attribute__((ext_vector_type(4)));

#define B_ 2
#define T_ 2048
#define C_ 2048
#define NH_ 16
#define NKV_ 4
#define HD_ 128
// (1/sqrt(128)) * log2(e) — folded into Q at rope_rms time
#define K2_ 0.12752004650581538f

__device__ __forceinline__ u16 f2bf(float f) {
    unsigned u = __builtin_bit_cast(unsigned, f);
    unsigned r = u + 0x7FFFu + ((u >> 16) & 1u);
    return (u16)(r >> 16);
}

__device__ __forceinline__ void gl16(const void* g, void* l) {
    auto gp = reinterpret_cast<const __attribute__((address_space(1))) unsigned*>(
        reinterpret_cast<uintptr_t>(g));
    auto lp = reinterpret_cast<__attribute__((address_space(3))) unsigned*>(
        reinterpret_cast<uintptr_t>(l));
    __builtin_amdgcn_global_load_lds(gp, lp, 16, 0, 0);
}

// ---------- transpose + fp32->bf16 convert: in [2048][N] -> out [N][2048] ----------
__global__ void transpose_conv(const float* __restrict__ in, u16* __restrict__ out, int N) {
    __shared__ float tile[32][33];
    int n0 = blockIdx.x * 32, k0 = blockIdx.y * 32;
    int tx = threadIdx.x, ty = threadIdx.y;  // 32 x 8
#pragma unroll
    for (int i = 0; i < 4; ++i)
        tile[ty * 4 + i][tx] = in[(size_t)(k0 + ty * 4 + i) * N + n0 + tx];
    __syncthreads();
#pragma unroll
    for (int i = 0; i < 4; ++i)
        out[(size_t)(n0 + ty * 4 + i) * 2048 + k0 + tx] = f2bf(tile[tx][ty * 4 + i]);
}

// ---------- fp32 -> bf16 convert (x), 4 elems/thread ----------
__global__ void convert4(const float4* __restrict__ in, u16* __restrict__ out) {
    int i = blockIdx.x * 256 + threadIdx.x;
    float4 v = in[i];
    u16x4 o;
    o[0] = f2bf(v.x); o[1] = f2bf(v.y); o[2] = f2bf(v.z); o[3] = f2bf(v.w);
    ((u16x4*)out)[i] = o;
}

// ---------- GEMM: C[M][N] f32 = A[M][K] bf16 * BT[N][K] bf16 (B transposed) ----------
__global__ __launch_bounds__(256, 2) void gemm_bf16(const u16* __restrict__ A,
                                                    const u16* __restrict__ BT,
                                                    float* __restrict__ C, int N, int K) {
    __shared__ __align__(16) u16 As[128 * 64];
    __shared__ __align__(16) u16 Bs[128 * 64];
    int t = threadIdx.x;
    int w = t >> 6, l = t & 63;
    int wr = w >> 1, wc = w & 1;
    int lg = l >> 4, lr = l & 15;
    int m0 = blockIdx.y * 128, n0 = blockIdx.x * 128;
    f32x4 acc[4][4] = {};

    int ar = t >> 3;
    int acb = (t & 7) * 16;
    const char* Abase = (const char*)(A + (size_t)(m0 + ar) * K) + acb;
    const char* Bbase = (const char*)(BT + (size_t)(n0 + ar) * K) + acb;
    char* AsB = (char*)As + t * 16;
    char* BsB = (char*)Bs + t * 16;

    for (int kt = 0; kt < K; kt += 64) {
        if (kt) __syncthreads();
#pragma unroll
        for (int i = 0; i < 4; ++i) {
            gl16(Abase + (size_t)(i * 32) * K * 2 + (size_t)kt * 2, AsB + i * 4096);
            gl16(Bbase + (size_t)(i * 32) * K * 2 + (size_t)kt * 2, BsB + i * 4096);
        }
        __syncthreads();
#pragma unroll
        for (int kk = 0; kk < 2; ++kk) {
            bf16x8 af[4], bfr[4];
#pragma unroll
            for (int m = 0; m < 4; ++m)
                af[m] = *(const bf16x8*)(As + (wr * 64 + m * 16 + lr) * 64 + kk * 32 + lg * 8);
#pragma unroll
            for (int n = 0; n < 4; ++n)
                bfr[n] = *(const bf16x8*)(Bs + (wc * 64 + n * 16 + lr) * 64 + kk * 32 + lg * 8);
#pragma unroll
            for (int m = 0; m < 4; ++m)
#pragma unroll
                for (int n = 0; n < 4; ++n)
                    acc[m][n] = __builtin_amdgcn_mfma_f32_16x16x32_bf16(af[m], bfr[n], acc[m][n], 0, 0, 0);
        }
    }
#pragma unroll
    for (int m = 0; m < 4; ++m) {
        int row = m0 + wr * 64 + m * 16 + lg * 4;
#pragma unroll
        for (int n = 0; n < 4; ++n) {
            int col = n0 + wc * 64 + n * 16 + lr;
            float* Cp = C + (size_t)row * N + col;
#pragma unroll
            for (int r = 0; r < 4; ++r)
                Cp[(size_t)r * N] = acc[m][n][r];
        }
    }
}

// ---------- RoPE + RMSNorm on q and k. One wave per 128-elem head-vector ----------
// q additionally pre-scaled by K2_ (softmax scale folded into Q, log2 domain)
__global__ void rope_rms(const float* __restrict__ qkv, const float* __restrict__ cs,
                         const float* __restrict__ sn, u16* __restrict__ qh,
                         u16* __restrict__ kh) {
    int task = blockIdx.x * 4 + (threadIdx.x >> 6);
    int l = threadIdx.x & 63;
    const float* in;
    u16* out;
    int tpos;
    float post = 1.0f;
    if (task < 65536) {               // q: 4096 rows * 16 heads
        int row = task >> 4, h = task & 15;
        in = qkv + (size_t)row * 3072 + h * 128;
        int b = row >> 11; tpos = row & 2047;
        out = qh + ((size_t)(b * NH_ + h) * T_ + tpos) * HD_;
        post = K2_;
    } else {                          // k: 4096 rows * 4 heads
        int t2 = task - 65536;
        int row = t2 >> 2, h = t2 & 3;
        in = qkv + (size_t)row * 3072 + 2048 + h * 128;
        int b = row >> 11; tpos = row & 2047;
        out = kh + ((size_t)(b * NKV_ + h) * T_ + tpos) * HD_;
    }
    float x1 = in[l], x2 = in[l + 64];
    float c = cs[tpos * 64 + l], s = sn[tpos * 64 + l];
    float o1 = x1 * c + x2 * s;
    float o2 = -x1 * s + x2 * c;
    float ss = o1 * o1 + o2 * o2;
#pragma unroll
    for (int m = 1; m < 64; m <<= 1) ss += __shfl_xor(ss, m);
    float r = rsqrtf(ss * (1.0f / 128.0f) + 1.1920929e-07f) * post;
    out[l] = f2bf(o1 * r);
    out[l + 64] = f2bf(o2 * r);
}

// ---------- V extract + transpose: qkv [4096][3072] f32 -> vt [B*NKV][128][2048] bf16 ----------
__global__ void transpose_v(const float* __restrict__ qkv, u16* __restrict__ vt) {
    __shared__ float tile[32][33];
    int t0 = blockIdx.x * 32;   // 64
    int d0 = blockIdx.y * 32;   // 4
    int bk = blockIdx.z;        // 8 = b*4+kvh
    int b = bk >> 2, kvh = bk & 3;
    int tx = threadIdx.x, ty = threadIdx.y;  // 32 x 8
#pragma unroll
    for (int i = 0; i < 4; ++i)
        tile[ty * 4 + i][tx] =
            qkv[(size_t)(b * 2048 + t0 + ty * 4 + i) * 3072 + 2560 + kvh * 128 + d0 + tx];
    __syncthreads();
#pragma unroll
    for (int i = 0; i < 4; ++i)
        vt[((size_t)bk * 128 + d0 + ty * 4 + i) * 2048 + t0 + tx] = f2bf(tile[tx][ty * 4 + i]);
}

// ---------- causal GQA flash attention: 8 waves (4 heads x 2 strip-pairs), shared LDS K/V ----------
// Q [B][NH][T][128], K [B][NKV][T][128], Vt [B][NKV][128][T] bf16 -> Y [B*T][2048] bf16
// grid = 256 blocks x 512 thr. Every block: exactly 33 kv-iters of 64 keys.
// LDS: Ks dbuf 32KB + Vs dbuf 32KB + P 18KB = 82KB (dynamic).
__global__ __launch_bounds__(512, 1) void attn(const u16* __restrict__ Q,
                                               const u16* __restrict__ Kk,
                                               const u16* __restrict__ V,
                                               u16* __restrict__ Y) {
    extern __shared__ __align__(16) u16 sm[];
    u16* Ks = sm;            // [2][64*128]  (row=key, 256B/row, XOR-swizzled granules)
    u16* Vs = sm + 16384;    // [2][128*64]  (row=dim, 128B/row, XOR-swizzled granules)
    u16* Pb = sm + 32768;    // [8][16*72]

    int bid = blockIdx.x;
    int xcd = bid & 7;
    int b = xcd >> 2, kvh = xcd & 3;
    int sp2 = bid >> 3;                 // 0..31
    int t = threadIdx.x;
    int w = t >> 6, l = t & 63;
    int lg = l >> 4, lr = l & 15;
    int h = kvh * 4 + (w & 3);
    int j = sp2 * 2 + (w >> 2);         // 0..63: strips (j, 127-j)
    int qwA = j * 16, qwB = (127 - j) * 16;
    int NA = j / 4 + 1;                 // phase-A iters; NB = 33-NA (same for all 8 waves)

    const u16* Qp = Q + (size_t)(b * NH_ + h) * T_ * HD_;
    const u16* Kp = Kk + (size_t)(b * NKV_ + kvh) * T_ * HD_;
    const u16* Vp = V + (size_t)(b * NKV_ + kvh) * HD_ * T_;
    u16* Yp = Y + (size_t)(b * T_) * 2048 + h * HD_;
    u16* Pw = Pb + w * 1152;

    int g0 = t, g1 = t + 512;
    // staging: K granule g: row=g>>4, col=g&15, src col pre-unswizzled col^(row&15)
    //          V granule g: row=g>>3, col=g&7,  src col pre-unswizzled col^(row&7)
    auto stage = [&](int kv0, int buf) {
        const char* Kb = (const char*)Kp + (size_t)kv0 * 256;
        const char* Vb = (const char*)Vp + (size_t)kv0 * 2;
        char* Kd = (char*)(Ks + buf * 8192);
        char* Vd = (char*)(Vs + buf * 8192);
        gl16(Kb + (g0 >> 4) * 256 + (((g0 & 15) ^ ((g0 >> 4) & 15)) * 16), Kd + g0 * 16);
        gl16(Kb + (g1 >> 4) * 256 + (((g1 & 15) ^ ((g1 >> 4) & 15)) * 16), Kd + g1 * 16);
        gl16(Vb + (size_t)(g0 >> 3) * 4096 + (((g0 & 7) ^ ((g0 >> 3) & 7)) * 16), Vd + g0 * 16);
        gl16(Vb + (size_t)(g1 >> 3) * 4096 + (((g1 & 7) ^ ((g1 >> 3) & 7)) * 16), Vd + g1 * 16);
    };

    bf16x8 aq[4];
    auto loadQ = [&](int qw2) {
#pragma unroll
        for (int ch = 0; ch < 4; ++ch)
            aq[ch] = *(const bf16x8*)(Qp + (size_t)(qw2 + lr) * HD_ + ch * 32 + lg * 8);
    };

    f32x4 acc[8] = {};
    float m2[4], lp_[4];
#pragma unroll
    for (int r = 0; r < 4; ++r) { m2[r] = -1e30f; lp_[r] = 0.0f; }

    auto epi = [&](int qw2) {
#pragma unroll
        for (int r = 0; r < 4; ++r) {
            float lt = lp_[r];
            lt += __shfl_xor(lt, 1);
            lt += __shfl_xor(lt, 2);
            lt += __shfl_xor(lt, 4);
            lt += __shfl_xor(lt, 8);
            float inv = 1.0f / lt;
#pragma unroll
            for (int oc = 0; oc < 8; ++oc)
                Yp[(size_t)(qw2 + lg * 4 + r) * 2048 + oc * 16 + lr] = f2bf(acc[oc][r] * inv);
        }
    };

    loadQ(qwA);
    int qw = qwA;
    stage(0, 0);

    for (int gi = 0; gi < 33; ++gi) {
        asm volatile("s_waitcnt vmcnt(0)" ::: "memory");
        __builtin_amdgcn_s_barrier();
        __builtin_amdgcn_sched_barrier(0);
        int cur = gi & 1;
        if (gi < 32) {
            int gn = gi + 1;
            stage((gn < NA ? gn : gn - NA) * 64, cur ^ 1);
        }
        if (gi == NA) {
            epi(qwA);
#pragma unroll
            for (int oc = 0; oc < 8; ++oc) acc[oc] = f32x4{0.f, 0.f, 0.f, 0.f};
#pragma unroll
            for (int r = 0; r < 4; ++r) { m2[r] = -1e30f; lp_[r] = 0.0f; }
            loadQ(qwB);
            qw = qwB;
        }
        int kv0 = (gi < NA ? gi : gi - NA) * 64;
        int kbase = cur * 8192;

        // ---- S = Q K^T (16 MFMA from swizzled LDS) ----
        f32x4 sc[4] = {};
        __builtin_amdgcn_s_setprio(1);
#pragma unroll
        for (int ch = 0; ch < 4; ++ch)
#pragma unroll
            for (int kf = 0; kf < 4; ++kf) {
                bf16x8 bk = *(const bf16x8*)&Ks[kbase + (kf * 16 + lr) * 128 + (((ch * 4 + lg) ^ lr) * 8)];
                sc[kf] = __builtin_amdgcn_mfma_f32_16x16x32_bf16(aq[ch], bk, sc[kf], 0, 0, 0);
            }
        __builtin_amdgcn_s_setprio(0);

        // ---- V ds_reads issued early; latency hides under softmax ----
        bf16x8 bv[16];
#pragma unroll
        for (int oc = 0; oc < 8; ++oc)
#pragma unroll
            for (int kk = 0; kk < 2; ++kk)
                bv[oc * 2 + kk] = *(const bf16x8*)&Vs[kbase + (oc * 16 + lr) * 64 +
                                                     (((kk * 4 + lg) ^ (lr & 7)) * 8)];

        // ---- mask + row max (log2 domain, Q pre-scaled) ----
        bool nm = (kv0 + 63 >= qw);
        float sv[4][4], mx[4];
#pragma unroll
        for (int r = 0; r < 4; ++r) {
            int row = qw + lg * 4 + r;
#pragma unroll
            for (int kf = 0; kf < 4; ++kf) {
                float x = sc[kf][r];
                if (nm) {
                    int key = kv0 + kf * 16 + lr;
                    x = (key > row) ? -1e38f : x;
                }
                sv[r][kf] = x;
            }
            mx[r] = fmaxf(fmaxf(sv[r][0], sv[r][1]), fmaxf(sv[r][2], sv[r][3]));
        }
#pragma unroll
        for (int r = 0; r < 4; ++r) {
            float m = mx[r];
            m = fmaxf(m, __shfl_xor(m, 1));
            m = fmaxf(m, __shfl_xor(m, 2));
            m = fmaxf(m, __shfl_xor(m, 4));
            m = fmaxf(m, __shfl_xor(m, 8));
            mx[r] = m;
        }
        // ---- defer-max rescale (THR=8, log2 domain) ----
        bool upd = false;
#pragma unroll
        for (int r = 0; r < 4; ++r) upd |= (mx[r] > m2[r] + 8.0f);
        if (__any(upd)) {
#pragma unroll
            for (int r = 0; r < 4; ++r) {
                float mn = fmaxf(m2[r], mx[r]);
                float rs = exp2f(m2[r] - mn);
                m2[r] = mn;
                lp_[r] *= rs;
#pragma unroll
                for (int oc = 0; oc < 8; ++oc) acc[oc] *= rs;
            }
        }
        // ---- p = 2^(s-m), partial l, stage P ----
#pragma unroll
        for (int r = 0; r < 4; ++r) {
            float m = m2[r];
            float ps = 0.0f;
#pragma unroll
            for (int kf = 0; kf < 4; ++kf) {
                float p = exp2f(sv[r][kf] - m);
                ps += p;
                Pw[(lg * 4 + r) * 72 + kf * 16 + lr] = f2bf(p);
            }
            lp_[r] += ps;
        }
        // ---- O += P V ----
        bf16x8 ap[2];
#pragma unroll
        for (int kk = 0; kk < 2; ++kk)
            ap[kk] = *(const bf16x8*)&Pw[lr * 72 + kk * 32 + lg * 8];
        __builtin_amdgcn_s_setprio(1);
#pragma unroll
        for (int oc = 0; oc < 8; ++oc)
#pragma unroll
            for (int kk = 0; kk < 2; ++kk)
                acc[oc] = __builtin_amdgcn_mfma_f32_16x16x32_bf16(ap[kk], bv[oc * 2 + kk], acc[oc], 0, 0, 0);
        __builtin_amdgcn_s_setprio(0);
    }
    epi(qwB);
}

extern "C" void kernel_launch(void* const* d_in, const int* in_sizes, int n_in,
                              void* d_out, int out_size, void* d_ws, size_t ws_size,
                              hipStream_t stream) {
    const float* x    = (const float*)d_in[0];
    const float* cosT = (const float*)d_in[1];
    const float* sinT = (const float*)d_in[2];
    const float* wq   = (const float*)d_in[3];
    const float* wk   = (const float*)d_in[4];
    const float* wv   = (const float*)d_in[5];
    const float* wo   = (const float*)d_in[6];
    float* out = (float*)d_out;

    char* ws = (char*)d_ws;
    u16*   wqkvT = (u16*)(ws);                       // [3072][2048] bf16
    u16*   woT   = (u16*)(ws + 12582912);            // [2048][2048] bf16
    u16*   xb    = (u16*)(ws + 20971520);            // [4096][2048] bf16
    float* qkv   = (float*)(ws + 37748736);          // [4096][3072] f32
    u16*   qh    = (u16*)(ws + 88080384);            // [2][16][2048][128] bf16
    u16*   kh    = (u16*)(ws + 104857600);           // [2][4][2048][128] bf16
    u16*   vt    = (u16*)(ws + 109051904);           // [2][4][128][2048] bf16 (V^T)
    u16*   y     = xb;                               // reuse (xb dead after GEMM1)

    static int smem_set = 0;
    if (!smem_set) {
        hipFuncSetAttribute(reinterpret_cast<const void*>(&attn),
                            hipFuncAttributeMaxDynamicSharedMemorySize, 83968);
        smem_set = 1;
    }

    transpose_conv<<<dim3(64, 64), dim3(32, 8), 0, stream>>>(wq, wqkvT, 2048);
    transpose_conv<<<dim3(16, 64), dim3(32, 8), 0, stream>>>(wk, wqkvT + (size_t)2048 * 2048, 512);
    transpose_conv<<<dim3(16, 64), dim3(32, 8), 0, stream>>>(wv, wqkvT + (size_t)2560 * 2048, 512);
    transpose_conv<<<dim3(64, 64), dim3(32, 8), 0, stream>>>(wo, woT, 2048);
    convert4<<<8192, 256, 0, stream>>>((const float4*)x, xb);

    gemm_bf16<<<dim3(24, 32), 256, 0, stream>>>(xb, wqkvT, qkv, 3072, 2048);

    rope_rms<<<20480, 256, 0, stream>>>(qkv, cosT, sinT, qh, kh);
    transpose_v<<<dim3(64, 4, 8), dim3(32, 8), 0, stream>>>(qkv, vt);

    attn<<<256, 512, 83968, stream>>>(qh, kh, vt, y);

    gemm_bf16<<<dim3(16, 32), 256, 0, stream>>>(y, woT, out, 2048, 2048);
}